// Round 17
// baseline (400.111 us; speedup 1.0000x reference)
//
#include <hip/hip_runtime.h>
#include <stdint.h>

// SimpleAttention v17: persistent 256 blocks x 4 tiles, 512 threads (2 waves/SIMD
// -> 256-VGPR budget, escaping hipcc's 64-reg cap on 1024-thr blocks).
// v12/v13-verified math: per-thread now 2 rows (i=slot, slot+16; fw identical),
// wave handles 4 t's. Junction prefetch: next tile's row-0 a-loads issued after
// c3's stageC frees cre, flying under mfma(3)+dump(1).

typedef unsigned int uint_t;
typedef float  f32x4   __attribute__((ext_vector_type(4)));
typedef short  short8v __attribute__((ext_vector_type(8)));

#define SYNCX() asm volatile("s_waitcnt lgkmcnt(0)\n\ts_barrier" ::: "memory")

constexpr int Bq = 16, Cq = 3072, Tq = 2048;
constexpr int TT = 32, TILES = 64;
constexpr int NBLK = 256;                // persistent; 4 tiles each
constexpr size_t ATT_OFF = (size_t)Bq * 2048 * Tq;
constexpr int TBS = 4224;
constexpr int LDS_BYTES = 135168;        // staging (32*TBS) == dump [1024][33] f32

__global__ __launch_bounds__(512, 1) void attn_v17(const float* __restrict__ x,
                                                   const float* __restrict__ xi,
                                                   float* __restrict__ out)
{
    __shared__ __align__(16) unsigned char smem[LDS_BYTES];
    uint_t*    LW = (uint_t*)smem;
    uint64_t*  LQ = (uint64_t*)smem;
    float*     LF = (float*)smem;

    const int tid  = (int)threadIdx.x;
    const int tl   = tid & 31;           // t
    const int slot = tid >> 5;           // 0..15: rows {slot, slot+16}
    const int blk  = (int)blockIdx.x;

    // staging constants (fw(slot) == fw(slot+16))
    const int fw  = ((slot >> 2) & 3) ^ (slot & 3);
    const int TBw = tl * TBS + (tl & 7) * 16;

    // mfma constants: wave wv owns t = 4wv + q, q = 0..3
    const int l   = tid & 63;
    const int wv  = tid >> 6;            // 0..7
    const int frd = ((l >> 2) & 3) ^ (l & 3);
    const int kbr = (((l >> 4) ^ frd) & 3) * 16;
    const int rA  = (l & 15) * 64;

    float  p0[64], p1[64];
    uint_t pk0[32], pk1[32];
    float  cre[64];                      // 2 C-rows per chunk
    f32x4  acc[4][2][2];                 // [q][s][dt]

    // ---- prologue: load p0 (row slot) for tile 0 ----
    {
        const int n = blk * 4;
        const int b0 = n >> 6, t00 = (n & 63) * TT;
        const float* xb  = x  + (size_t)b0 * Cq * Tq + t00 + tl;
        const float* xib = xi + (size_t)b0 * Cq * Tq + t00 + tl;
#pragma unroll
        for (int j = 0; j < 32; ++j) p0[j]      = xb [(size_t)(slot * 96 + j) * Tq];
#pragma unroll
        for (int j = 0; j < 32; ++j) p0[j + 32] = xib[(size_t)(slot * 96 + j) * Tq];
    }

#pragma unroll 1
    for (int s = 0; s < 4; ++s) {
        const int n  = blk * 4 + s;
        const int b  = n >> 6;
        const int t0 = (n & 63) * TT;
        const float* xb  = x  + (size_t)b * Cq * Tq + t0 + tl;
        const float* xib = xi + (size_t)b * Cq * Tq + t0 + tl;

        // ---- phase A row 0 (i = slot): softmax from p0 -> attn + pk0 ----
        {
            const int i = slot;
            float m = p0[0];
#pragma unroll
            for (int j = 1; j < 64; ++j) m = fmaxf(m, p0[j]);
            float sm = 0.f;
#pragma unroll
            for (int j = 0; j < 64; ++j) { p0[j] = __expf(p0[j] - m); sm += p0[j]; }
            const float inv = 1.f / sm;
#pragma unroll
            for (int j = 0; j < 64; ++j) p0[j] *= inv;

            // row-1 loads fly under the rest of row-0 processing
#pragma unroll
            for (int j = 0; j < 32; ++j) p1[j]      = xb [(size_t)((slot + 16) * 96 + j) * Tq];
#pragma unroll
            for (int j = 0; j < 32; ++j) p1[j + 32] = xib[(size_t)((slot + 16) * 96 + j) * Tq];

            float* ao = out + ATT_OFF + ((size_t)(b * 32 + i) * 32) * Tq + t0 + tl;
#pragma unroll
            for (int j = 0; j < 32; ++j) {
                float v = p0[j] + ((j == i) ? 0.f : p0[j + 32]);
                __builtin_nontemporal_store(v, &ao[(size_t)j * Tq]);
            }
#pragma unroll
            for (int k = 0; k < 32; ++k) {
                uint_t b0_ = __float_as_uint(p0[2 * k]);
                uint_t b1_ = __float_as_uint(p0[2 * k + 1]);
                uint_t lo = (b0_ + 0x7fffu + ((b0_ >> 16) & 1u)) >> 16;
                uint_t hi = (b1_ + 0x7fffu + ((b1_ >> 16) & 1u)) >> 16;
                pk0[k] = lo | (hi << 16);
            }
        }

        // chunk-0 ctx loads (both rows) fly under row-1 softmax
        {
            const float* sp0 = x + (size_t)b * Cq * Tq + (size_t)(32 + slot) * Tq + t0 + tl;
            const float* sp1 = x + (size_t)b * Cq * Tq + (size_t)(32 + slot + 16) * Tq + t0 + tl;
#pragma unroll
            for (int kk = 0; kk < 32; ++kk) cre[kk]      = sp0[(size_t)kk * 96 * Tq];
#pragma unroll
            for (int kk = 0; kk < 32; ++kk) cre[kk + 32] = sp1[(size_t)kk * 96 * Tq];
        }

        // ---- phase A row 1 (i = slot+16) ----
        {
            const int i = slot + 16;
            float m = p1[0];
#pragma unroll
            for (int j = 1; j < 64; ++j) m = fmaxf(m, p1[j]);
            float sm = 0.f;
#pragma unroll
            for (int j = 0; j < 64; ++j) { p1[j] = __expf(p1[j] - m); sm += p1[j]; }
            const float inv = 1.f / sm;
#pragma unroll
            for (int j = 0; j < 64; ++j) p1[j] *= inv;

            float* ao = out + ATT_OFF + ((size_t)(b * 32 + i) * 32) * Tq + t0 + tl;
#pragma unroll
            for (int j = 0; j < 32; ++j) {
                float v = p1[j] + ((j == i) ? 0.f : p1[j + 32]);
                __builtin_nontemporal_store(v, &ao[(size_t)j * Tq]);
            }
#pragma unroll
            for (int k = 0; k < 32; ++k) {
                uint_t b0_ = __float_as_uint(p1[2 * k]);
                uint_t b1_ = __float_as_uint(p1[2 * k + 1]);
                uint_t lo = (b0_ + 0x7fffu + ((b0_ >> 16) & 1u)) >> 16;
                uint_t hi = (b1_ + 0x7fffu + ((b1_ >> 16) & 1u)) >> 16;
                pk1[k] = lo | (hi << 16);
            }
        }

        auto issueQ = [&](int q) {       // q = dh*2+jh, literal calls (1..3)
            const int dh = q >> 1, jh = q & 1;
            const float* src = (jh == 0) ? x : xi;
            const float* sp0 = src + (size_t)b * Cq * Tq
                             + (size_t)(32 + dh * 32 + slot) * Tq + t0 + tl;
            const float* sp1 = sp0 + (size_t)16 * Tq;
#pragma unroll
            for (int kk = 0; kk < 32; ++kk) cre[kk]      = sp0[(size_t)kk * 96 * Tq];
#pragma unroll
            for (int kk = 0; kk < 32; ++kk) cre[kk + 32] = sp1[(size_t)kk * 96 * Tq];
        };
        auto stageP = [&](int jh) {      // both rows
#pragma unroll
            for (int m = 0; m < 16; m += 2) {
                const int kbx  = (m >> 2) ^ fw;
                const int byte = TBw + slot * 64 + kbx * 16 + ((2 * m) & 7) * 2;
                LQ[byte >> 3] = (uint64_t)pk0[jh * 16 + m] |
                                ((uint64_t)pk0[jh * 16 + m + 1] << 32);
                const int byte2 = byte + 16 * 64;
                LQ[byte2 >> 3] = (uint64_t)pk1[jh * 16 + m] |
                                 ((uint64_t)pk1[jh * 16 + m + 1] << 32);
            }
        };
        auto stageC = [&]() {            // both rows from cre
#pragma unroll
            for (int kk = 0; kk < 32; kk += 2) {
                const int kbx  = (kk >> 3) ^ fw;
                uint_t a0 = __float_as_uint(cre[kk]);
                uint_t a1 = __float_as_uint(cre[kk + 1]);
                uint_t h0 = (a0 + 0x7fffu + ((a0 >> 16) & 1u)) >> 16;
                uint_t h1 = (a1 + 0x7fffu + ((a1 >> 16) & 1u)) >> 16;
                const int byte = TBw + 2048 + slot * 64 + kbx * 16 + (kk & 7) * 2;
                LW[byte >> 2] = h0 | (h1 << 16);
                uint_t c0 = __float_as_uint(cre[kk + 32]);
                uint_t c1 = __float_as_uint(cre[kk + 33]);
                uint_t g0 = (c0 + 0x7fffu + ((c0 >> 16) & 1u)) >> 16;
                uint_t g1 = (c1 + 0x7fffu + ((c1 >> 16) & 1u)) >> 16;
                const int byte2 = byte + 16 * 64;
                LW[byte2 >> 2] = g0 | (g1 << 16);
            }
        };
        auto accClr = [&]() {
#pragma unroll
            for (int q = 0; q < 4; ++q)
#pragma unroll
                for (int s_ = 0; s_ < 2; ++s_)
#pragma unroll
                    for (int dt = 0; dt < 2; ++dt) acc[q][s_][dt] = (f32x4)(0.f);
        };
        auto mfmaChunk = [&]() {
#pragma unroll
            for (int q = 0; q < 4; ++q) {
                const int tloc = 4 * wv + q;
                const int base = tloc * TBS + (tloc & 7) * 16;
                const short8v A0 = *(const short8v*)(smem + base        + rA + kbr);
                const short8v A1 = *(const short8v*)(smem + base + 1024 + rA + kbr);
                const short8v B0 = *(const short8v*)(smem + base + 2048 + rA + kbr);
                const short8v B1 = *(const short8v*)(smem + base + 3072 + rA + kbr);
                acc[q][0][0] = __builtin_amdgcn_mfma_f32_16x16x32_bf16(A0, B0, acc[q][0][0], 0, 0, 0);
                acc[q][0][1] = __builtin_amdgcn_mfma_f32_16x16x32_bf16(A0, B1, acc[q][0][1], 0, 0, 0);
                acc[q][1][0] = __builtin_amdgcn_mfma_f32_16x16x32_bf16(A1, B0, acc[q][1][0], 0, 0, 0);
                acc[q][1][1] = __builtin_amdgcn_mfma_f32_16x16x32_bf16(A1, B1, acc[q][1][1], 0, 0, 0);
            }
        };
        auto dump = [&](int dh) {
#pragma unroll
            for (int q = 0; q < 4; ++q)
#pragma unroll
                for (int s_ = 0; s_ < 2; ++s_)
#pragma unroll
                    for (int dt = 0; dt < 2; ++dt)
#pragma unroll
                        for (int ri = 0; ri < 4; ++ri) {
                            const int ii = s_ * 16 + (l >> 4) * 4 + ri;
                            const int dl = dt * 16 + (l & 15);
                            LF[(ii * 32 + dl) * 33 + 4 * wv + q] = acc[q][s_][dt][ri];
                        }
            SYNCX();
            float* ob = out + (size_t)b * 2048 * Tq + t0 + tl;
#pragma unroll 8
            for (int kk = 0; kk < 32; ++kk) {
                const int ch  = kk * 64 + dh * 32 + slot;
                __builtin_nontemporal_store(LF[(kk * 32 + slot) * 33 + tl],
                                            &ob[(size_t)ch * Tq]);
                const int ch2 = ch + 16;
                __builtin_nontemporal_store(LF[(kk * 32 + slot + 16) * 33 + tl],
                                            &ob[(size_t)ch2 * Tq]);
            }
            SYNCX();
        };

        // ---- chunks (v13 order) ----
        accClr();
        stageP(0); stageC();             // c0 (dh0 jh0)
        SYNCX();
        issueQ(1); mfmaChunk();          // c0
        SYNCX();
        stageP(1); stageC();             // c1 (dh0 jh1)
        SYNCX();
        issueQ(2); mfmaChunk();          // c1
        SYNCX();
        dump(0);
        accClr();
        stageP(0); stageC();             // c2 (dh1 jh0)
        SYNCX();
        issueQ(3); mfmaChunk();          // c2
        SYNCX();
        stageP(1); stageC();             // c3 (dh1 jh1)
        // junction: cre free -> prefetch next tile's row-0 a-part
        if (s < 3) {
            const int n1 = blk * 4 + s + 1;
            const int b1 = n1 >> 6, t01 = (n1 & 63) * TT;
            const float* xb1  = x  + (size_t)b1 * Cq * Tq + t01 + tl;
            const float* xib1 = xi + (size_t)b1 * Cq * Tq + t01 + tl;
#pragma unroll
            for (int j = 0; j < 32; ++j) p0[j]      = xb1 [(size_t)(slot * 96 + j) * Tq];
#pragma unroll
            for (int j = 0; j < 32; ++j) p0[j + 32] = xib1[(size_t)(slot * 96 + j) * Tq];
        }
        SYNCX();
        mfmaChunk();                     // c3
        SYNCX();
        dump(1);
    }
}

extern "C" void kernel_launch(void* const* d_in, const int* in_sizes, int n_in,
                              void* d_out, int out_size, void* d_ws, size_t ws_size,
                              hipStream_t stream) {
    const float* x  = (const float*)d_in[0];
    const float* xi = (const float*)d_in[1];
    float* out = (float*)d_out;
    attn_v17<<<dim3(NBLK), dim3(512), 0, stream>>>(x, xi, out);
}

// Round 18
// 391.117 us; speedup vs baseline: 1.0230x; 1.0230x over previous
//
#include <hip/hip_runtime.h>
#include <stdint.h>

// SimpleAttention v18: v14 verbatim per-tile, persistent 256 blocks x 4 tiles
// (removes per-CU block-boundary LDS-realloc/queue-drain gaps; zero new state).

typedef unsigned int uint_t;
typedef float  f32x4   __attribute__((ext_vector_type(4)));
typedef short  short8v __attribute__((ext_vector_type(8)));

#define SYNCX() asm volatile("s_waitcnt lgkmcnt(0)\n\ts_barrier" ::: "memory")

constexpr int Bq = 16, Cq = 3072, Tq = 2048;
constexpr int TT = 32, TILES = 64;
constexpr int NBLK = 256;                 // persistent; 4 consecutive tiles each
constexpr size_t ATT_OFF = (size_t)Bq * 2048 * Tq;
constexpr int TBS = 4224;                 // per-t staging block stride (bytes)
constexpr int LDS_BYTES = 135168;         // 32*TBS == 1024*33*4 (dump union)

__global__ __launch_bounds__(1024, 1) void attn_v18(const float* __restrict__ x,
                                                    const float* __restrict__ xi,
                                                    float* __restrict__ out)
{
    __shared__ __align__(16) unsigned char smem[LDS_BYTES];
    uint_t*    LW = (uint_t*)smem;
    uint64_t*  LQ = (uint64_t*)smem;
    float*     LF = (float*)smem;

    const int tid  = (int)threadIdx.x;
    const int tl   = tid & 31;           // t (phase A / staging / stores)
    const int slot = tid >> 5;           // i (phase A, P-stage), d (C-stage, store)

    // staging-side constants (row = slot)
    const int fw  = ((slot >> 2) & 3) ^ (slot & 3);      // kb-XOR swizzle
    const int TBw = tl * TBS + (tl & 7) * 16;            // t-block byte base

    // mfma-side constants
    const int l   = tid & 63;
    const int wv  = tid >> 6;                            // wave owns t = 2wv, 2wv+1
    const int frd = ((l >> 2) & 3) ^ (l & 3);
    const int kbr = (((l >> 4) ^ frd) & 3) * 16;
    const int rA  = (l & 15) * 64;

#pragma unroll 1
    for (int s = 0; s < 4; ++s) {
        const int n  = (int)blockIdx.x * 4 + s;
        const int b    = n >> 6;
        const int tile = n & (TILES - 1);
        const int t0   = tile * TT;

        const float* xb  = x  + (size_t)b * Cq * Tq + t0 + tl;
        const float* xib = xi + (size_t)b * Cq * Tq + t0 + tl;

        uint_t pk[32];
        float  cre[32];                  // ctx prefetch buffer (one chunk ahead)

        auto issue = [&](int c) {        // c = dh*2 + jh, literal-called only
            const int dh = c >> 1, jh = c & 1;
            const float* src = (jh == 0) ? x : xi;
            const float* sp  = src + (size_t)b * Cq * Tq
                             + (size_t)(32 + dh * 32 + slot) * Tq + t0 + tl;
#pragma unroll
            for (int kk = 0; kk < 32; ++kk) cre[kk] = sp[(size_t)kk * 96 * Tq];
        };

        // ---- phase A: softmax row i=slot; attn out; pack p -> pk ----
        {
            const int i = slot;
            float p[64];
#pragma unroll
            for (int j = 0; j < 32; ++j) p[j]      = xb [(size_t)(i * 96 + j) * Tq];
#pragma unroll
            for (int j = 0; j < 32; ++j) p[j + 32] = xib[(size_t)(i * 96 + j) * Tq];

            issue(0);                    // chunk-0 ctx loads fly under softmax

            float m = p[0];
#pragma unroll
            for (int j = 1; j < 64; ++j) m = fmaxf(m, p[j]);
            float sm = 0.f;
#pragma unroll
            for (int j = 0; j < 64; ++j) { p[j] = __expf(p[j] - m); sm += p[j]; }
            const float inv = 1.f / sm;
#pragma unroll
            for (int j = 0; j < 64; ++j) p[j] *= inv;

            float* ao = out + ATT_OFF + ((size_t)(b * 32 + i) * 32) * Tq + t0 + tl;
#pragma unroll
            for (int j = 0; j < 32; ++j) {
                float v = p[j] + ((j == i) ? 0.f : p[j + 32]);
                __builtin_nontemporal_store(v, &ao[(size_t)j * Tq]);
            }
#pragma unroll
            for (int k = 0; k < 32; ++k) {
                uint_t b0 = __float_as_uint(p[2 * k]);
                uint_t b1 = __float_as_uint(p[2 * k + 1]);
                uint_t lo = (b0 + 0x7fffu + ((b0 >> 16) & 1u)) >> 16;
                uint_t hi = (b1 + 0x7fffu + ((b1 >> 16) & 1u)) >> 16;
                pk[k] = lo | (hi << 16);
            }
        }

        auto stageP = [&](int jh) {
#pragma unroll
            for (int m = 0; m < 16; m += 2) {            // pairs (m, m+1) share kb
                const int kbx  = (m >> 2) ^ fw;
                const int byte = TBw + slot * 64 + kbx * 16 + ((2 * m) & 7) * 2;
                uint64_t w = (uint64_t)pk[jh * 16 + m] |
                             ((uint64_t)pk[jh * 16 + m + 1] << 32);
                LQ[byte >> 3] = w;
            }
        };
        auto stageC = [&]() {                             // consumes cre[]
#pragma unroll
            for (int kk = 0; kk < 32; kk += 2) {
                uint_t b0 = __float_as_uint(cre[kk]);
                uint_t b1 = __float_as_uint(cre[kk + 1]);
                uint_t h0 = (b0 + 0x7fffu + ((b0 >> 16) & 1u)) >> 16;
                uint_t h1 = (b1 + 0x7fffu + ((b1 >> 16) & 1u)) >> 16;
                const int kbx  = (kk >> 3) ^ fw;
                const int byte = TBw + 2048 + slot * 64 + kbx * 16 + (kk & 7) * 2;
                LW[byte >> 2] = h0 | (h1 << 16);
            }
        };

        f32x4 acc[2][2][2];                              // [q][sv][dt]
        auto accClr = [&]() {
#pragma unroll
            for (int q = 0; q < 2; ++q)
#pragma unroll
                for (int sv = 0; sv < 2; ++sv)
#pragma unroll
                    for (int dt = 0; dt < 2; ++dt) acc[q][sv][dt] = (f32x4)(0.f);
        };
        auto mfmaChunk = [&]() {
#pragma unroll
            for (int q = 0; q < 2; ++q) {
                const int tloc = 2 * wv + q;
                const int base = tloc * TBS + (tloc & 7) * 16;
                const short8v A0 = *(const short8v*)(smem + base        + rA + kbr);
                const short8v A1 = *(const short8v*)(smem + base + 1024 + rA + kbr);
                const short8v B0 = *(const short8v*)(smem + base + 2048 + rA + kbr);
                const short8v B1 = *(const short8v*)(smem + base + 3072 + rA + kbr);
                acc[q][0][0] = __builtin_amdgcn_mfma_f32_16x16x32_bf16(A0, B0, acc[q][0][0], 0, 0, 0);
                acc[q][0][1] = __builtin_amdgcn_mfma_f32_16x16x32_bf16(A0, B1, acc[q][0][1], 0, 0, 0);
                acc[q][1][0] = __builtin_amdgcn_mfma_f32_16x16x32_bf16(A1, B0, acc[q][1][0], 0, 0, 0);
                acc[q][1][1] = __builtin_amdgcn_mfma_f32_16x16x32_bf16(A1, B1, acc[q][1][1], 0, 0, 0);
            }
        };
        auto dump = [&](int dh) {                        // olds transpose + stores
#pragma unroll
            for (int q = 0; q < 2; ++q)
#pragma unroll
                for (int sv = 0; sv < 2; ++sv)
#pragma unroll
                    for (int dt = 0; dt < 2; ++dt)
#pragma unroll
                        for (int ri = 0; ri < 4; ++ri) {
                            const int ii = sv * 16 + (l >> 4) * 4 + ri;
                            const int dl = dt * 16 + (l & 15);
                            LF[(ii * 32 + dl) * 33 + 2 * wv + q] = acc[q][sv][dt][ri];
                        }
            SYNCX();
            float* ob = out + (size_t)b * 2048 * Tq + t0 + tl;
#pragma unroll 8
            for (int kk = 0; kk < 32; ++kk) {
                const int ch = kk * 64 + dh * 32 + slot;
                __builtin_nontemporal_store(LF[(kk * 32 + slot) * 33 + tl],
                                            &ob[(size_t)ch * Tq]);
            }
            SYNCX();                                     // region reused next
        };

        // ---- pipelined chunks: c = dh*2 + jh ----
        accClr();
        stageP(0); stageC();
        SYNCX();
        issue(1);
        mfmaChunk();
        SYNCX();
        stageP(1); stageC();
        SYNCX();
        issue(2);
        mfmaChunk();
        SYNCX();
        dump(0);
        accClr();
        stageP(0); stageC();
        SYNCX();
        issue(3);
        mfmaChunk();
        SYNCX();
        stageP(1); stageC();
        SYNCX();
        mfmaChunk();
        SYNCX();
        dump(1);
    }
}

extern "C" void kernel_launch(void* const* d_in, const int* in_sizes, int n_in,
                              void* d_out, int out_size, void* d_ws, size_t ws_size,
                              hipStream_t stream) {
    const float* x  = (const float*)d_in[0];
    const float* xi = (const float*)d_in[1];
    float* out = (float*)d_out;
    attn_v18<<<dim3(NBLK), dim3(1024), 0, stream>>>(x, xi, out);
}

// Round 19
// 258.654 us; speedup vs baseline: 1.5469x; 1.5121x over previous
//
#include <hip/hip_runtime.h>
#include <stdint.h>

// SimpleAttention v19 == v13 (measured best: 258.6 us timed).
// MFMA core (m92/m97-verified fragment recipe), TT=32 full-line coalescing,
// depth-1 register prefetch of ctx staging loads, packed b32/b64 LDS writes.
// Structural box (measured v5..v18): TT=32 forced by line granularity;
// 132KB LDS -> 1 block/CU; 1024 thr -> 128 reg/lane budget (64 arch + 32 AGPR
// + pk[32] + cre[32] = full); deeper prefetch or geometry changes spill/lose
// coalescing. This schedule is the box's optimum.

typedef unsigned int uint_t;
typedef float  f32x4   __attribute__((ext_vector_type(4)));
typedef short  short8v __attribute__((ext_vector_type(8)));

constexpr int Bq = 16, Cq = 3072, Tq = 2048;
constexpr int TT = 32, TILES = 64, NBLK = Bq * TILES;   // 1024 blocks
constexpr size_t ATT_OFF = (size_t)Bq * 2048 * Tq;
constexpr int TBS = 4224;                 // per-t staging block stride (bytes)
constexpr int LDS_BYTES = 135168;         // 32*TBS == 1024*33*4 (unioned with olds)

__global__ __launch_bounds__(1024, 1) void attn_v19(const float* __restrict__ x,
                                                    const float* __restrict__ xi,
                                                    float* __restrict__ out)
{
    __shared__ __align__(16) unsigned char smem[LDS_BYTES];
    uint_t*    LW = (uint_t*)smem;
    uint64_t*  LQ = (uint64_t*)smem;
    float*     LF = (float*)smem;

    const int tid  = (int)threadIdx.x;
    const int b    = (int)blockIdx.x >> 6;
    const int tile = (int)blockIdx.x & (TILES - 1);
    const int t0   = tile * TT;
    const int tl   = tid & 31;           // t for phase A / staging / stores
    const int slot = tid >> 5;           // 0..31: i (phase A, P-stage), d (C-stage, store)

    const float* xb  = x  + (size_t)b * Cq * Tq + t0 + tl;
    const float* xib = xi + (size_t)b * Cq * Tq + t0 + tl;

    uint_t pk[32];
    float  cre[32];                      // ctx prefetch buffer (one chunk ahead)

    auto issue = [&](int c) {            // c = dh*2 + jh, literal-called only
        const int dh = c >> 1, jh = c & 1;
        const float* src = (jh == 0) ? x : xi;
        const float* sp  = src + (size_t)b * Cq * Tq
                         + (size_t)(32 + dh * 32 + slot) * Tq + t0 + tl;
#pragma unroll
        for (int kk = 0; kk < 32; ++kk) cre[kk] = sp[(size_t)kk * 96 * Tq];
    };

    {
        const int i = slot;
        float p[64];
#pragma unroll
        for (int j = 0; j < 32; ++j) p[j]      = xb [(size_t)(i * 96 + j) * Tq];
#pragma unroll
        for (int j = 0; j < 32; ++j) p[j + 32] = xib[(size_t)(i * 96 + j) * Tq];
        float m = p[0];
#pragma unroll
        for (int j = 1; j < 64; ++j) m = fmaxf(m, p[j]);
        float s = 0.f;
#pragma unroll
        for (int j = 0; j < 64; ++j) { p[j] = __expf(p[j] - m); s += p[j]; }
        const float inv = 1.f / s;
#pragma unroll
        for (int j = 0; j < 64; ++j) p[j] *= inv;

        float* ao = out + ATT_OFF + ((size_t)(b * 32 + i) * 32) * Tq + t0 + tl;
#pragma unroll
        for (int j = 0; j < 32; ++j) {
            float v = p[j] + ((j == i) ? 0.f : p[j + 32]);
            __builtin_nontemporal_store(v, &ao[(size_t)j * Tq]);
        }
#pragma unroll
        for (int k = 0; k < 32; ++k) {
            uint_t b0 = __float_as_uint(p[2 * k]);
            uint_t b1 = __float_as_uint(p[2 * k + 1]);
            uint_t lo = (b0 + 0x7fffu + ((b0 >> 16) & 1u)) >> 16;
            uint_t hi = (b1 + 0x7fffu + ((b1 >> 16) & 1u)) >> 16;
            pk[k] = lo | (hi << 16);
        }
    }
    issue(0);                            // chunk-0 ctx loads fly from here

    // staging-side constants (row = slot)
    const int fw  = ((slot >> 2) & 3) ^ (slot & 3);      // kb-XOR swizzle
    const int TBw = tl * TBS + (tl & 7) * 16;            // t-block byte base

    // mfma-side constants
    const int l   = tid & 63;
    const int wv  = tid >> 6;                            // wave owns t = 2wv, 2wv+1
    const int frd = ((l >> 2) & 3) ^ (l & 3);
    const int kbr = (((l >> 4) ^ frd) & 3) * 16;
    const int rA  = (l & 15) * 64;

    auto stageP = [&](int jh) {
#pragma unroll
        for (int m = 0; m < 16; m += 2) {                // pairs (m, m+1) share kb
            const int kbx  = (m >> 2) ^ fw;
            const int byte = TBw + slot * 64 + kbx * 16 + ((2 * m) & 7) * 2;
            uint64_t w = (uint64_t)pk[jh * 16 + m] |
                         ((uint64_t)pk[jh * 16 + m + 1] << 32);
            LQ[byte >> 3] = w;
        }
    };
    auto stageC = [&]() {                                 // consumes cre[]
#pragma unroll
        for (int kk = 0; kk < 32; kk += 2) {
            uint_t b0 = __float_as_uint(cre[kk]);
            uint_t b1 = __float_as_uint(cre[kk + 1]);
            uint_t h0 = (b0 + 0x7fffu + ((b0 >> 16) & 1u)) >> 16;
            uint_t h1 = (b1 + 0x7fffu + ((b1 >> 16) & 1u)) >> 16;
            const int kbx  = (kk >> 3) ^ fw;
            const int byte = TBw + 2048 + slot * 64 + kbx * 16 + (kk & 7) * 2;
            LW[byte >> 2] = h0 | (h1 << 16);
        }
    };

    f32x4 acc[2][2][2];                                  // [q][s][dt]
    auto accClr = [&]() {
#pragma unroll
        for (int q = 0; q < 2; ++q)
#pragma unroll
            for (int s = 0; s < 2; ++s)
#pragma unroll
                for (int dt = 0; dt < 2; ++dt) acc[q][s][dt] = (f32x4)(0.f);
    };
    auto mfmaChunk = [&]() {
#pragma unroll
        for (int q = 0; q < 2; ++q) {
            const int tloc = 2 * wv + q;
            const int base = tloc * TBS + (tloc & 7) * 16;
            const short8v A0 = *(const short8v*)(smem + base        + rA + kbr);
            const short8v A1 = *(const short8v*)(smem + base + 1024 + rA + kbr);
            const short8v B0 = *(const short8v*)(smem + base + 2048 + rA + kbr);
            const short8v B1 = *(const short8v*)(smem + base + 3072 + rA + kbr);
            acc[q][0][0] = __builtin_amdgcn_mfma_f32_16x16x32_bf16(A0, B0, acc[q][0][0], 0, 0, 0);
            acc[q][0][1] = __builtin_amdgcn_mfma_f32_16x16x32_bf16(A0, B1, acc[q][0][1], 0, 0, 0);
            acc[q][1][0] = __builtin_amdgcn_mfma_f32_16x16x32_bf16(A1, B0, acc[q][1][0], 0, 0, 0);
            acc[q][1][1] = __builtin_amdgcn_mfma_f32_16x16x32_bf16(A1, B1, acc[q][1][1], 0, 0, 0);
        }
    };
    auto dump = [&](int dh) {                            // olds transpose + stores
#pragma unroll
        for (int q = 0; q < 2; ++q)
#pragma unroll
            for (int s = 0; s < 2; ++s)
#pragma unroll
                for (int dt = 0; dt < 2; ++dt)
#pragma unroll
                    for (int ri = 0; ri < 4; ++ri) {
                        const int ii = s * 16 + (l >> 4) * 4 + ri;
                        const int dl = dt * 16 + (l & 15);
                        LF[(ii * 32 + dl) * 33 + 2 * wv + q] = acc[q][s][dt][ri];
                    }
        __syncthreads();
        float* ob = out + (size_t)b * 2048 * Tq + t0 + tl;
#pragma unroll 8
        for (int kk = 0; kk < 32; ++kk) {
            const int ch = kk * 64 + dh * 32 + slot;
            __builtin_nontemporal_store(LF[(kk * 32 + slot) * 33 + tl],
                                        &ob[(size_t)ch * Tq]);
        }
        __syncthreads();                                 // region reused next
    };

    // ---- pipelined chunks: c = dh*2 + jh ----
    accClr();
    // c = 0 (dh0, jh0)
    stageP(0); stageC();
    __syncthreads();
    issue(1);
    mfmaChunk();
    __syncthreads();
    // c = 1 (dh0, jh1)
    stageP(1); stageC();
    __syncthreads();
    issue(2);
    mfmaChunk();
    __syncthreads();
    dump(0);
    accClr();
    // c = 2 (dh1, jh0)
    stageP(0); stageC();
    __syncthreads();
    issue(3);
    mfmaChunk();
    __syncthreads();
    // c = 3 (dh1, jh1)
    stageP(1); stageC();
    __syncthreads();
    mfmaChunk();
    __syncthreads();
    dump(1);
}

extern "C" void kernel_launch(void* const* d_in, const int* in_sizes, int n_in,
                              void* d_out, int out_size, void* d_ws, size_t ws_size,
                              hipStream_t stream) {
    const float* x  = (const float*)d_in[0];
    const float* xi = (const float*)d_in[1];
    float* out = (float*)d_out;
    attn_v19<<<dim3(NBLK), dim3(1024), 0, stream>>>(x, xi, out);
}